// Round 2
// baseline (305.325 us; speedup 1.0000x reference)
//
#include <hip/hip_runtime.h>

#define DF 128
#define CAP 40    // max in-degree bucket capacity; in-deg ~ Poisson(12), realized max ~30
#define TROWS 64  // gemm tile rows

// ---------------------------------------------------------------------------
// 4-way-unrolled per-node aggregation:
//   acc = sum_i w_i * rsqrt(deg[src_i]) * H[src_i][4t..4t+3]
// Records loaded 4-at-a-time via aligned int4 pairs so 4 independent 512B
// gathers (+4 deg broadcasts) are in flight per iteration (MLP ~4x).
// bucket is 16B-aligned: csr base 512B-aligned, node*CAP*8 = node*320 (16|320).
// ---------------------------------------------------------------------------
__device__ __forceinline__ float4 agg_node(const float4* __restrict__ H4,
                                           const int2* __restrict__ bucket,
                                           int m, const float* __restrict__ deg,
                                           int t)
{
    float4 acc = make_float4(0.f, 0.f, 0.f, 0.f);
    int i = 0;
    for (; i + 4 <= m; i += 4) {
        const int4* b4 = (const int4*)(bucket + i);   // i%4==0 -> 32B steps, aligned
        const int4 p0 = b4[0];                        // records i, i+1
        const int4 p1 = b4[1];                        // records i+2, i+3
        const float w0 = __int_as_float(p0.y) * rsqrtf(deg[p0.x]);
        const float w1 = __int_as_float(p0.w) * rsqrtf(deg[p0.z]);
        const float w2 = __int_as_float(p1.y) * rsqrtf(deg[p1.x]);
        const float w3 = __int_as_float(p1.w) * rsqrtf(deg[p1.z]);
        const float4 h0 = H4[(size_t)p0.x * 32 + t];
        const float4 h1 = H4[(size_t)p0.z * 32 + t];
        const float4 h2 = H4[(size_t)p1.x * 32 + t];
        const float4 h3 = H4[(size_t)p1.z * 32 + t];
        acc.x = fmaf(w0, h0.x, acc.x);
        acc.y = fmaf(w0, h0.y, acc.y);
        acc.z = fmaf(w0, h0.z, acc.z);
        acc.w = fmaf(w0, h0.w, acc.w);
        acc.x = fmaf(w1, h1.x, acc.x);
        acc.y = fmaf(w1, h1.y, acc.y);
        acc.z = fmaf(w1, h1.z, acc.z);
        acc.w = fmaf(w1, h1.w, acc.w);
        acc.x = fmaf(w2, h2.x, acc.x);
        acc.y = fmaf(w2, h2.y, acc.y);
        acc.z = fmaf(w2, h2.z, acc.z);
        acc.w = fmaf(w2, h2.w, acc.w);
        acc.x = fmaf(w3, h3.x, acc.x);
        acc.y = fmaf(w3, h3.y, acc.y);
        acc.z = fmaf(w3, h3.z, acc.z);
        acc.w = fmaf(w3, h3.w, acc.w);
    }
    for (; i < m; ++i) {
        const int2 rec = bucket[i];
        const float wv = __int_as_float(rec.y) * rsqrtf(deg[rec.x]);
        const float4 h = H4[(size_t)rec.x * 32 + t];
        acc.x = fmaf(wv, h.x, acc.x);
        acc.y = fmaf(wv, h.y, acc.y);
        acc.z = fmaf(wv, h.z, acc.z);
        acc.w = fmaf(wv, h.w, acc.w);
    }
    return acc;
}

// ---------------------------------------------------------------------------
// Shared register-blocked GEMM core: H[n0:n0+64] = Xs @ W^T + b.
// Assumes Xs (64x128 row-major) is fully populated by the caller (no sync
// needed by caller: first __syncthreads inside the k0 loop covers it).
// ---------------------------------------------------------------------------
__device__ __forceinline__ void gemm_from_lds(
    float* __restrict__ Xs, float* __restrict__ Wsk,
    const float* __restrict__ W, const float* __restrict__ b,
    float* __restrict__ H, int nrows, int n0, int tid)
{
    const int rgrp = tid >> 5;
    const int cgrp = tid & 31;

    float4 acc[8];
    const float4 bias = ((const float4*)b)[cgrp];
#pragma unroll
    for (int r = 0; r < 8; ++r) acc[r] = bias;

    const float4* Xs4 = (const float4*)Xs;
    const float4* Ws4 = (const float4*)Wsk;

    for (int k0 = 0; k0 < DF; k0 += 32) {
        __syncthreads();
#pragma unroll
        for (int i = 0; i < 4; ++i) {
            int idx = tid + i * 256;
            int c   = idx >> 3;
            int kk  = idx & 7;
            float4 v = ((const float4*)(W + (size_t)c * DF + k0))[kk];
            int kb = kk * 4;
            Wsk[(kb + 0) * DF + c] = v.x;
            Wsk[(kb + 1) * DF + c] = v.y;
            Wsk[(kb + 2) * DF + c] = v.z;
            Wsk[(kb + 3) * DF + c] = v.w;
        }
        __syncthreads();

#pragma unroll
        for (int kk = 0; kk < 8; ++kk) {
            const int kb = (k0 >> 2) + kk;
            float4 w0 = Ws4[(kk * 4 + 0) * 32 + cgrp];
            float4 w1 = Ws4[(kk * 4 + 1) * 32 + cgrp];
            float4 w2 = Ws4[(kk * 4 + 2) * 32 + cgrp];
            float4 w3 = Ws4[(kk * 4 + 3) * 32 + cgrp];
#pragma unroll
            for (int r = 0; r < 8; ++r) {
                float4 x4 = Xs4[(rgrp * 8 + r) * 32 + kb];
                acc[r].x = fmaf(x4.x, w0.x, acc[r].x);
                acc[r].y = fmaf(x4.x, w0.y, acc[r].y);
                acc[r].z = fmaf(x4.x, w0.z, acc[r].z);
                acc[r].w = fmaf(x4.x, w0.w, acc[r].w);
                acc[r].x = fmaf(x4.y, w1.x, acc[r].x);
                acc[r].y = fmaf(x4.y, w1.y, acc[r].y);
                acc[r].z = fmaf(x4.y, w1.z, acc[r].z);
                acc[r].w = fmaf(x4.y, w1.w, acc[r].w);
                acc[r].x = fmaf(x4.z, w2.x, acc[r].x);
                acc[r].y = fmaf(x4.z, w2.y, acc[r].y);
                acc[r].z = fmaf(x4.z, w2.z, acc[r].z);
                acc[r].w = fmaf(x4.z, w2.w, acc[r].w);
                acc[r].x = fmaf(x4.w, w3.x, acc[r].x);
                acc[r].y = fmaf(x4.w, w3.y, acc[r].y);
                acc[r].z = fmaf(x4.w, w3.z, acc[r].z);
                acc[r].w = fmaf(x4.w, w3.w, acc[r].w);
            }
        }
    }

#pragma unroll
    for (int r = 0; r < 8; ++r) {
        int n = n0 + rgrp * 8 + r;
        if (n < nrows) ((float4*)(H + (size_t)n * DF))[cgrp] = acc[r];
    }
}

// ==== fused: blocks [0,gemmBlocks) = GEMM1 tile; rest = CSR build ====
// GEMM: H = X @ W^T + b (256 thr, 64x128 tile, thread 8x4)
// build: deg[row]+=w; pos=cnt[col]++; csr[col*CAP+pos]=(row,w)
__global__ __launch_bounds__(256) void build_gemm_kernel(
    const float* __restrict__ X, const float* __restrict__ W,
    const float* __restrict__ b, float* __restrict__ H, int nrows,
    const int* __restrict__ row, const int* __restrict__ col,
    const float* __restrict__ ew,
    float* __restrict__ deg, int* __restrict__ cnt, int2* __restrict__ csr,
    int E, int gemmBlocks)
{
    __shared__ float Xs[TROWS * DF];
    __shared__ float Wsk[32 * DF];

    const int tid = threadIdx.x;

    if (blockIdx.x >= gemmBlocks) {
        // ---------------- build part ----------------
        int e = (blockIdx.x - gemmBlocks) * 256 + tid;
        if (e < E) {
            int r = row[e], c = col[e];
            float wv = ew[e];
            atomicAdd(&deg[r], wv);              // fire-and-forget
            int pos = atomicAdd(&cnt[c], 1);     // returning
            if (pos < CAP)
                csr[(size_t)c * CAP + pos] = make_int2(r, __float_as_int(wv));
        }
        return;
    }

    // ---------------- gemm part: stage X tile, then shared GEMM core ----
    const int n0 = blockIdx.x * TROWS;
#pragma unroll
    for (int i = 0; i < 8; ++i) {
        int idx = tid + i * 256;
        int r   = idx >> 5;
        int kk  = idx & 31;
        int n   = n0 + r;
        float4 v = make_float4(0.f, 0.f, 0.f, 0.f);
        if (n < nrows) v = ((const float4*)(X + (size_t)n * DF))[kk];
        ((float4*)Xs)[idx] = v;
    }
    gemm_from_lds(Xs, Wsk, W, b, H, nrows, n0, tid);
}

// ==== fused layer-boundary kernel: agg1 (+ReLU) -> LDS -> GEMM2 ====
// Each block owns 64 output rows. The gemm2 tile for rows [n0,n0+64) only
// needs agg1 of those rows, so aggregate straight into the Xs LDS tile
// (no 25.6MB global round-trip, one fewer launch, agg/gemm phases of
// different blocks overlap on the CU).
__global__ __launch_bounds__(256) void agg_gemm_kernel(
    const float4* __restrict__ H4,      // layer-1 linear output (gather src)
    const int2* __restrict__ csr, const int* __restrict__ cnt,
    const float* __restrict__ deg,
    const float* __restrict__ W, const float* __restrict__ b,
    float* __restrict__ O, int N)
{
    __shared__ float Xs[TROWS * DF];
    __shared__ float Wsk[32 * DF];

    const int tid = threadIdx.x;
    const int g   = tid >> 5;        // half-wave group 0..7
    const int t   = tid & 31;
    const int n0  = blockIdx.x * TROWS;

    // ---- agg phase: group g computes rows g*8 .. g*8+7 into Xs ----
#pragma unroll
    for (int j = 0; j < 8; ++j) {
        const int r    = g * 8 + j;
        const int node = n0 + r;
        float4 acc = make_float4(0.f, 0.f, 0.f, 0.f);
        if (node < N) {
            int m = cnt[node];
            if (m > CAP) m = CAP;
            const int2* bucket = csr + (size_t)node * CAP;
            acc = agg_node(H4, bucket, m, deg, t);
            const float dcol = rsqrtf(deg[node]);
            acc.x = fmaxf(acc.x * dcol, 0.f);
            acc.y = fmaxf(acc.y * dcol, 0.f);
            acc.z = fmaxf(acc.z * dcol, 0.f);
            acc.w = fmaxf(acc.w * dcol, 0.f);
        }
        ((float4*)Xs)[r * 32 + t] = acc;   // row-major 64x128, same layout GEMM reads
    }
    // (first __syncthreads inside gemm_from_lds's k0 loop fences Xs writes)
    gemm_from_lds(Xs, Wsk, W, b, O, N, n0, tid);
}

// ---- final pull aggregation (layer 2), 4-way-unrolled gather ----
__global__ void agg_kernel(const float4* __restrict__ H4,
                           const int2* __restrict__ csr, const int* __restrict__ cnt,
                           const float* __restrict__ deg,
                           float4* __restrict__ O4, int N)
{
    const int gid  = blockIdx.x * blockDim.x + threadIdx.x;
    const int node = gid >> 5;
    const int t    = gid & 31;
    if (node >= N) return;
    int m = cnt[node];
    if (m > CAP) m = CAP;
    const int2* bucket = csr + (size_t)node * CAP;
    float4 acc = agg_node(H4, bucket, m, deg, t);
    const float dcol = rsqrtf(deg[node]);
    acc.x *= dcol; acc.y *= dcol; acc.z *= dcol; acc.w *= dcol;
    O4[(size_t)node * 32 + t] = acc;
}

extern "C" void kernel_launch(void* const* d_in, const int* in_sizes, int n_in,
                              void* d_out, int out_size, void* d_ws, size_t ws_size,
                              hipStream_t stream) {
    const float* x  = (const float*)d_in[0];
    const int*   ei = (const int*)d_in[1];
    const float* ew = (const float*)d_in[2];
    const float* W1 = (const float*)d_in[3];
    const float* b1 = (const float*)d_in[4];
    const float* W2 = (const float*)d_in[5];
    const float* b2 = (const float*)d_in[6];
    float* out = (float*)d_out;

    const int E = in_sizes[2];        // 600000
    const int N = in_sizes[0] / DF;   // 50000
    const int* row = ei;
    const int* col = ei + E;

    char* ws = (char*)d_ws;
    size_t offb = 0;
    auto alloc = [&](size_t bytes) { char* p = ws + offb; offb = (offb + bytes + 511) & ~(size_t)511; return p; };
    float* deg  = (float*)alloc((size_t)2 * N * 4);      // deg | cnt combined (one memset)
    int*   cnt  = (int*)(deg + N);
    int2*  csr  = (int2*)alloc((size_t)N * CAP * 8);     // packed (src, w) records
    float* h1   = (float*)alloc((size_t)N * DF * 4);     // layer-1 linear out
    float* h2   = (float*)alloc((size_t)N * DF * 4);     // layer-2 linear out (distinct from h1: agg phase gathers h1 while gemm phase writes h2)
    (void)ws_size;

    hipMemsetAsync(deg, 0, (size_t)2 * N * 4, stream);

    const int TB = 256;
    const int eblocks = (E + TB - 1) / TB;
    const int gemm_blocks = (N + TROWS - 1) / TROWS;

    // ---- fused: gemm1 (blocks [0,gemm_blocks)) + CSR build (rest) ----
    build_gemm_kernel<<<gemm_blocks + eblocks, 256, 0, stream>>>(
        x, W1, b1, h1, N, row, col, ew, deg, cnt, csr, E, gemm_blocks);

    // ---- fused: agg1 (+ReLU) -> LDS -> gemm2 ----
    agg_gemm_kernel<<<gemm_blocks, 256, 0, stream>>>(
        (const float4*)h1, csr, cnt, deg, W2, b2, h2, N);

    // ---- final aggregation ----
    const int agg_blocks = (N * 32 + TB - 1) / TB;
    agg_kernel<<<agg_blocks, TB, 0, stream>>>((const float4*)h2, csr, cnt, deg,
                                              (float4*)out, N);
}

// Round 4
// 281.630 us; speedup vs baseline: 1.0841x; 1.0841x over previous
//
#include <hip/hip_runtime.h>

#define DF 128
#define CAP 40    // max in-degree bucket capacity; in-deg ~ Poisson(12), realized max ~30

// NOTE: parameter names must not collide with float4 member names (x,y,z,w):
// macro substitution rewrites identifiers even after '.', so a param named
// 'w' would turn 'v.w' into 'v.<arg>'.
#define FMA4(a4, s, v)                                              \
    a4.x = fmaf(s, v.x, a4.x); a4.y = fmaf(s, v.y, a4.y);           \
    a4.z = fmaf(s, v.z, a4.z); a4.w = fmaf(s, v.w, a4.w)

// ---------------------------------------------------------------------------
// 4-way-unrolled tail aggregation starting at record i (i % 4 == 0):
//   acc += sum w_i * rsqrt(deg[src_i]) * H[src_i][4t..4t+3]
// bucket is 16B-aligned (csr base 512B-aligned, node*CAP*8 = node*320).
// ---------------------------------------------------------------------------
__device__ __forceinline__ float4 agg_tail(const float4* __restrict__ H4,
                                           const int2* __restrict__ bucket,
                                           int i, int m,
                                           const float* __restrict__ deg,
                                           int t, float4 acc)
{
    for (; i + 4 <= m; i += 4) {
        const int4* b4 = (const int4*)(bucket + i);
        const int4 p0 = b4[0];
        const int4 p1 = b4[1];
        const float4 h0 = H4[(size_t)p0.x * 32 + t];
        const float4 h1 = H4[(size_t)p0.z * 32 + t];
        const float4 h2 = H4[(size_t)p1.x * 32 + t];
        const float4 h3 = H4[(size_t)p1.z * 32 + t];
        const float s0 = __int_as_float(p0.y) * rsqrtf(deg[p0.x]);
        const float s1 = __int_as_float(p0.w) * rsqrtf(deg[p0.z]);
        const float s2 = __int_as_float(p1.y) * rsqrtf(deg[p1.x]);
        const float s3 = __int_as_float(p1.w) * rsqrtf(deg[p1.z]);
        FMA4(acc, s0, h0);
        FMA4(acc, s1, h1);
        FMA4(acc, s2, h2);
        FMA4(acc, s3, h3);
    }
    for (; i < m; ++i) {
        const int2 rec = bucket[i];
        const float sv = __int_as_float(rec.y) * rsqrtf(deg[rec.x]);
        const float4 hv = H4[(size_t)rec.x * 32 + t];
        FMA4(acc, sv, hv);
    }
    return acc;
}

// ---------------------------------------------------------------------------
// Two-node interleaved aggregation: 8 independent 512B gathers in flight per
// iteration (2x the MLP of the single-node loop) over the common prefix,
// then per-node tails. Summation order within each node is unchanged.
// ---------------------------------------------------------------------------
__device__ __forceinline__ void agg2(const float4* __restrict__ H4,
                                     const int2* __restrict__ bA, int mA,
                                     const int2* __restrict__ bB, int mB,
                                     const float* __restrict__ deg, int t,
                                     float4& accA, float4& accB)
{
    const int mc = mA < mB ? mA : mB;
    int i = 0;
    for (; i + 4 <= mc; i += 4) {
        const int4 a0 = ((const int4*)(bA + i))[0];
        const int4 a1 = ((const int4*)(bA + i))[1];
        const int4 c0 = ((const int4*)(bB + i))[0];
        const int4 c1 = ((const int4*)(bB + i))[1];
        const float4 hA0 = H4[(size_t)a0.x * 32 + t];
        const float4 hA1 = H4[(size_t)a0.z * 32 + t];
        const float4 hA2 = H4[(size_t)a1.x * 32 + t];
        const float4 hA3 = H4[(size_t)a1.z * 32 + t];
        const float4 hB0 = H4[(size_t)c0.x * 32 + t];
        const float4 hB1 = H4[(size_t)c0.z * 32 + t];
        const float4 hB2 = H4[(size_t)c1.x * 32 + t];
        const float4 hB3 = H4[(size_t)c1.z * 32 + t];
        const float sA0 = __int_as_float(a0.y) * rsqrtf(deg[a0.x]);
        const float sA1 = __int_as_float(a0.w) * rsqrtf(deg[a0.z]);
        const float sA2 = __int_as_float(a1.y) * rsqrtf(deg[a1.x]);
        const float sA3 = __int_as_float(a1.w) * rsqrtf(deg[a1.z]);
        const float sB0 = __int_as_float(c0.y) * rsqrtf(deg[c0.x]);
        const float sB1 = __int_as_float(c0.w) * rsqrtf(deg[c0.z]);
        const float sB2 = __int_as_float(c1.y) * rsqrtf(deg[c1.x]);
        const float sB3 = __int_as_float(c1.w) * rsqrtf(deg[c1.z]);
        FMA4(accA, sA0, hA0);
        FMA4(accA, sA1, hA1);
        FMA4(accA, sA2, hA2);
        FMA4(accA, sA3, hA3);
        FMA4(accB, sB0, hB0);
        FMA4(accB, sB1, hB1);
        FMA4(accB, sB2, hB2);
        FMA4(accB, sB3, hB3);
    }
    accA = agg_tail(H4, bA, i, mA, deg, t, accA);
    accB = agg_tail(H4, bB, i, mB, deg, t, accB);
}

// ---------------------------------------------------------------------------
// Register-blocked GEMM core: H[n0 : n0+8*RPT] = Xs @ W^T + b.
// RPT = rows per thread (= rows per 32-lane group). Xs is (8*RPT) x 128
// row-major in LDS, fully populated by the caller (first __syncthreads in
// the k0 loop fences it). Wsk is a 32 x 128 k-slice of W, transposed.
// ---------------------------------------------------------------------------
template <int RPT>
__device__ __forceinline__ void gemm_from_lds(
    float* __restrict__ Xs, float* __restrict__ Wsk,
    const float* __restrict__ W, const float* __restrict__ b,
    float* __restrict__ H, int nrows, int n0, int tid)
{
    const int rgrp = tid >> 5;
    const int cgrp = tid & 31;

    float4 acc[RPT];
    const float4 bias = ((const float4*)b)[cgrp];
#pragma unroll
    for (int r = 0; r < RPT; ++r) acc[r] = bias;

    const float4* Xs4 = (const float4*)Xs;
    const float4* Ws4 = (const float4*)Wsk;

    for (int k0 = 0; k0 < DF; k0 += 32) {
        __syncthreads();
#pragma unroll
        for (int i = 0; i < 4; ++i) {
            int idx = tid + i * 256;
            int c   = idx >> 3;
            int kk  = idx & 7;
            float4 v = ((const float4*)(W + (size_t)c * DF + k0))[kk];
            int kb = kk * 4;
            Wsk[(kb + 0) * DF + c] = v.x;
            Wsk[(kb + 1) * DF + c] = v.y;
            Wsk[(kb + 2) * DF + c] = v.z;
            Wsk[(kb + 3) * DF + c] = v.w;
        }
        __syncthreads();

#pragma unroll
        for (int kk = 0; kk < 8; ++kk) {
            const int kb = (k0 >> 2) + kk;
            float4 w0 = Ws4[(kk * 4 + 0) * 32 + cgrp];
            float4 w1 = Ws4[(kk * 4 + 1) * 32 + cgrp];
            float4 w2 = Ws4[(kk * 4 + 2) * 32 + cgrp];
            float4 w3 = Ws4[(kk * 4 + 3) * 32 + cgrp];
#pragma unroll
            for (int r = 0; r < RPT; ++r) {
                float4 x4 = Xs4[(rgrp * RPT + r) * 32 + kb];
                acc[r].x = fmaf(x4.x, w0.x, acc[r].x);
                acc[r].y = fmaf(x4.x, w0.y, acc[r].y);
                acc[r].z = fmaf(x4.x, w0.z, acc[r].z);
                acc[r].w = fmaf(x4.x, w0.w, acc[r].w);
                acc[r].x = fmaf(x4.y, w1.x, acc[r].x);
                acc[r].y = fmaf(x4.y, w1.y, acc[r].y);
                acc[r].z = fmaf(x4.y, w1.z, acc[r].z);
                acc[r].w = fmaf(x4.y, w1.w, acc[r].w);
                acc[r].x = fmaf(x4.z, w2.x, acc[r].x);
                acc[r].y = fmaf(x4.z, w2.y, acc[r].y);
                acc[r].z = fmaf(x4.z, w2.z, acc[r].z);
                acc[r].w = fmaf(x4.z, w2.w, acc[r].w);
                acc[r].x = fmaf(x4.w, w3.x, acc[r].x);
                acc[r].y = fmaf(x4.w, w3.y, acc[r].y);
                acc[r].z = fmaf(x4.w, w3.z, acc[r].z);
                acc[r].w = fmaf(x4.w, w3.w, acc[r].w);
            }
        }
    }

#pragma unroll
    for (int r = 0; r < RPT; ++r) {
        int n = n0 + rgrp * RPT + r;
        if (n < nrows) ((float4*)(H + (size_t)n * DF))[cgrp] = acc[r];
    }
}

// ==== fused: blocks [0,gemmBlocks) = GEMM1 64-row tile; rest = CSR build ====
__global__ __launch_bounds__(256) void build_gemm_kernel(
    const float* __restrict__ X, const float* __restrict__ W,
    const float* __restrict__ b, float* __restrict__ H, int nrows,
    const int* __restrict__ row, const int* __restrict__ col,
    const float* __restrict__ ew,
    float* __restrict__ deg, int* __restrict__ cnt, int2* __restrict__ csr,
    int E, int gemmBlocks)
{
    __shared__ float Xs[64 * DF];
    __shared__ float Wsk[32 * DF];

    const int tid = threadIdx.x;

    if (blockIdx.x >= gemmBlocks) {
        // ---------------- build part ----------------
        int e = (blockIdx.x - gemmBlocks) * 256 + tid;
        if (e < E) {
            int r = row[e], c = col[e];
            float wv = ew[e];
            atomicAdd(&deg[r], wv);              // fire-and-forget
            int pos = atomicAdd(&cnt[c], 1);     // returning
            if (pos < CAP)
                csr[(size_t)c * CAP + pos] = make_int2(r, __float_as_int(wv));
        }
        return;
    }

    // ---------------- gemm part: stage X tile, then shared GEMM core ----
    const int n0 = blockIdx.x * 64;
#pragma unroll
    for (int i = 0; i < 8; ++i) {
        int idx = tid + i * 256;
        int r   = idx >> 5;
        int kk  = idx & 31;
        int n   = n0 + r;
        float4 v = make_float4(0.f, 0.f, 0.f, 0.f);
        if (n < nrows) v = ((const float4*)(X + (size_t)n * DF))[kk];
        ((float4*)Xs)[idx] = v;
    }
    gemm_from_lds<8>(Xs, Wsk, W, b, H, nrows, n0, tid);
}

// ==== fused layer boundary: agg1 (+ReLU) -> LDS -> GEMM2, 32-row tile ====
// 32-row tile => LDS 32KB (Xs 16K + Wsk 16K) => 4-5 blocks/CU (vs 3 at 48KB)
// and 1563 blocks (vs 782) so the extra occupancy is fillable. Each 32-lane
// group aggregates its 4 rows as 2 interleaved pairs (8 gathers in flight).
__global__ __launch_bounds__(256, 4) void agg_gemm_kernel(
    const float4* __restrict__ H4,      // layer-1 linear output (gather src)
    const int2* __restrict__ csr, const int* __restrict__ cnt,
    const float* __restrict__ deg,
    const float* __restrict__ W, const float* __restrict__ b,
    float* __restrict__ O, int N)
{
    __shared__ float Xs[32 * DF];
    __shared__ float Wsk[32 * DF];

    const int tid = threadIdx.x;
    const int g   = tid >> 5;        // group 0..7, owns rows g*4 .. g*4+3
    const int t   = tid & 31;
    const int n0  = blockIdx.x * 32;

#pragma unroll
    for (int jp = 0; jp < 2; ++jp) {
        const int rA = g * 4 + jp * 2;
        const int rB = rA + 1;
        const int nodeA = n0 + rA;
        const int nodeB = n0 + rB;
        int mA = 0, mB = 0;
        if (nodeA < N) { mA = cnt[nodeA]; if (mA > CAP) mA = CAP; }
        if (nodeB < N) { mB = cnt[nodeB]; if (mB > CAP) mB = CAP; }
        float4 accA = make_float4(0.f, 0.f, 0.f, 0.f);
        float4 accB = make_float4(0.f, 0.f, 0.f, 0.f);
        agg2(H4, csr + (size_t)nodeA * CAP, mA,
                 csr + (size_t)nodeB * CAP, mB, deg, t, accA, accB);
        if (nodeA < N) {
            const float d = rsqrtf(deg[nodeA]);
            accA.x = fmaxf(accA.x * d, 0.f); accA.y = fmaxf(accA.y * d, 0.f);
            accA.z = fmaxf(accA.z * d, 0.f); accA.w = fmaxf(accA.w * d, 0.f);
        }
        if (nodeB < N) {
            const float d = rsqrtf(deg[nodeB]);
            accB.x = fmaxf(accB.x * d, 0.f); accB.y = fmaxf(accB.y * d, 0.f);
            accB.z = fmaxf(accB.z * d, 0.f); accB.w = fmaxf(accB.w * d, 0.f);
        }
        ((float4*)Xs)[rA * 32 + t] = accA;   // zeros for OOB rows
        ((float4*)Xs)[rB * 32 + t] = accB;
    }
    // (first __syncthreads inside gemm_from_lds's k0 loop fences Xs writes)
    gemm_from_lds<4>(Xs, Wsk, W, b, O, N, n0, tid);
}

// ---- final pull aggregation (layer 2): 2 nodes per half-wave, interleaved --
__global__ __launch_bounds__(256) void agg_kernel(
    const float4* __restrict__ H4,
    const int2* __restrict__ csr, const int* __restrict__ cnt,
    const float* __restrict__ deg,
    float4* __restrict__ O4, int N)
{
    const int gid  = blockIdx.x * blockDim.x + threadIdx.x;
    const int half = gid >> 5;
    const int t    = gid & 31;
    const int nA   = half * 2;
    const int nB   = nA + 1;
    if (nA >= N) return;
    int mA = cnt[nA]; if (mA > CAP) mA = CAP;
    int mB = 0;
    if (nB < N) { mB = cnt[nB]; if (mB > CAP) mB = CAP; }
    float4 accA = make_float4(0.f, 0.f, 0.f, 0.f);
    float4 accB = make_float4(0.f, 0.f, 0.f, 0.f);
    agg2(H4, csr + (size_t)nA * CAP, mA,
             csr + (size_t)nB * CAP, mB, deg, t, accA, accB);
    const float dA = rsqrtf(deg[nA]);
    accA.x *= dA; accA.y *= dA; accA.z *= dA; accA.w *= dA;
    O4[(size_t)nA * 32 + t] = accA;
    if (nB < N) {
        const float dB = rsqrtf(deg[nB]);
        accB.x *= dB; accB.y *= dB; accB.z *= dB; accB.w *= dB;
        O4[(size_t)nB * 32 + t] = accB;
    }
}

extern "C" void kernel_launch(void* const* d_in, const int* in_sizes, int n_in,
                              void* d_out, int out_size, void* d_ws, size_t ws_size,
                              hipStream_t stream) {
    const float* x  = (const float*)d_in[0];
    const int*   ei = (const int*)d_in[1];
    const float* ew = (const float*)d_in[2];
    const float* W1 = (const float*)d_in[3];
    const float* b1 = (const float*)d_in[4];
    const float* W2 = (const float*)d_in[5];
    const float* b2 = (const float*)d_in[6];
    float* out = (float*)d_out;

    const int E = in_sizes[2];        // 600000
    const int N = in_sizes[0] / DF;   // 50000
    const int* row = ei;
    const int* col = ei + E;

    char* ws = (char*)d_ws;
    size_t offb = 0;
    auto alloc = [&](size_t bytes) { char* p = ws + offb; offb = (offb + bytes + 511) & ~(size_t)511; return p; };
    float* deg  = (float*)alloc((size_t)2 * N * 4);      // deg | cnt combined (one memset)
    int*   cnt  = (int*)(deg + N);
    int2*  csr  = (int2*)alloc((size_t)N * CAP * 8);     // packed (src, w) records
    float* h1   = (float*)alloc((size_t)N * DF * 4);     // layer-1 linear out
    float* h2   = (float*)alloc((size_t)N * DF * 4);     // layer-2 linear out
    (void)ws_size;

    hipMemsetAsync(deg, 0, (size_t)2 * N * 4, stream);

    const int TB = 256;
    const int eblocks = (E + TB - 1) / TB;
    const int gemm1_blocks = (N + 63) / 64;      // 64-row tiles
    const int agg_gemm_blocks = (N + 31) / 32;   // 32-row tiles

    // ---- fused: gemm1 + CSR build ----
    build_gemm_kernel<<<gemm1_blocks + eblocks, 256, 0, stream>>>(
        x, W1, b1, h1, N, row, col, ew, deg, cnt, csr, E, gemm1_blocks);

    // ---- fused: agg1 (+ReLU) -> LDS -> gemm2 ----
    agg_gemm_kernel<<<agg_gemm_blocks, 256, 0, stream>>>(
        (const float4*)h1, csr, cnt, deg, W2, b2, h2, N);

    // ---- final aggregation: 2 nodes per half-wave ----
    const int pairs = (N + 1) / 2;
    const int agg_blocks = (pairs * 32 + TB - 1) / TB;
    agg_kernel<<<agg_blocks, TB, 0, stream>>>((const float4*)h2, csr, cnt, deg,
                                              (float4*)out, N);
}